// Round 2
// baseline (759.571 us; speedup 1.0000x reference)
//
#include <hip/hip_runtime.h>

typedef unsigned short u16;
typedef __attribute__((ext_vector_type(8))) short bf16x8;
typedef __attribute__((ext_vector_type(4))) float f32x4;
typedef __attribute__((ext_vector_type(8))) unsigned short u16x8;
typedef __attribute__((ext_vector_type(4))) unsigned short u16x4;

#define B_ 4
#define S_ 2048
#define E_ 1024
#define H_ 16
#define D_ 64
#define F_ 4096
#define M_ 8192   // B*S tokens

__device__ __forceinline__ float bf2f(u16 u) {
    union { unsigned int i; float f; } v; v.i = ((unsigned int)u) << 16; return v.f;
}
__device__ __forceinline__ u16 f2bf(float f) {
    union { float f; unsigned int i; } v; v.f = f;
    unsigned int r = v.i + 0x7FFFu + ((v.i >> 16) & 1u);
    return (u16)(r >> 16);
}

// ---------------- cast x (f32 -> bf16), 8 elems/thread ----------------
__global__ __launch_bounds__(256) void cast_f32_bf16(const float* __restrict__ in,
                                                     u16* __restrict__ out) {
    const int i = blockIdx.x * 256 + threadIdx.x;
    const f32x4* p = (const f32x4*)in + (size_t)i * 2;
    f32x4 a = p[0], b = p[1];
    u16x8 o;
    o[0] = f2bf(a[0]); o[1] = f2bf(a[1]); o[2] = f2bf(a[2]); o[3] = f2bf(a[3]);
    o[4] = f2bf(b[0]); o[5] = f2bf(b[1]); o[6] = f2bf(b[2]); o[7] = f2bf(b[3]);
    *((u16x8*)out + i) = o;
}

// ---------------- transpose + cast: w[R][C] f32 -> wT[C][R] bf16 ----------------
__global__ __launch_bounds__(256) void transpose_cast(const float* __restrict__ w,
                                                      u16* __restrict__ wT,
                                                      int R, int C) {
    __shared__ float tile[32][33];
    const int tx = threadIdx.x & 31, ty = threadIdx.x >> 5;
    const int c0 = blockIdx.x * 32, r0 = blockIdx.y * 32;
#pragma unroll
    for (int i = 0; i < 4; ++i)
        tile[ty + i * 8][tx] = w[(size_t)(r0 + ty + i * 8) * C + c0 + tx];
    __syncthreads();
#pragma unroll
    for (int i = 0; i < 4; ++i)
        wT[(size_t)(c0 + ty + i * 8) * R + r0 + tx] = f2bf(tile[tx][ty + i * 8]);
}

// ---------------- concat q/k/v bias into [3072] f32 ----------------
__global__ __launch_bounds__(256) void concat_bias(const float* __restrict__ qb,
                                                   const float* __restrict__ kb,
                                                   const float* __restrict__ vb,
                                                   float* __restrict__ dst) {
    const int i = blockIdx.x * 256 + threadIdx.x;
    float v = (i < 1024) ? qb[i] : ((i < 2048) ? kb[i - 1024] : vb[i - 2048]);
    dst[i] = v;
}

// ---------------- bf16 GEMM: C[M,N] = A[M,K] * Bt[N,K]^T + bias (+relu) ----------------
// 128x128 tile, BK=64, 4 waves (2x2), 16x16x32 MFMA, global_load_lds staging.
__global__ __launch_bounds__(256) void gemm_bf16(const u16* __restrict__ A,
                                                 const u16* __restrict__ Bt,
                                                 const float* __restrict__ bias,
                                                 u16* __restrict__ C,
                                                 int N, int K, int relu) {
    __shared__ __align__(16) u16 As[128 * 64];
    __shared__ __align__(16) u16 Bs[128 * 64];
    const int tid = threadIdx.x;
    const int wid = tid >> 6, lane = tid & 63;
    const int mbase = blockIdx.y * 128, nbase = blockIdx.x * 128;
    const int wr = (wid >> 1) * 64, wc = (wid & 1) * 64;

    f32x4 acc[4][4];
    const f32x4 z = {0.f, 0.f, 0.f, 0.f};
#pragma unroll
    for (int m = 0; m < 4; ++m)
#pragma unroll
        for (int n = 0; n < 4; ++n) acc[m][n] = z;

    const int Lb = wid * 1024 + lane * 16;  // byte offset within 16KB tile
    const int kIters = K >> 6;

    for (int kb = 0; kb < kIters; ++kb) {
        __syncthreads();
#pragma unroll
        for (int c = 0; c < 4; ++c) {
            const int L = c * 4096 + Lb;
            const int row = L >> 7;        // 128 bytes per row (64 bf16)
            const int cbyte = L & 127;
            const u16* ga = A + (size_t)(mbase + row) * K + (kb << 6) + (cbyte >> 1);
            const u16* gb = Bt + (size_t)(nbase + row) * K + (kb << 6) + (cbyte >> 1);
            __builtin_amdgcn_global_load_lds(
                (const __attribute__((address_space(1))) void*)ga,
                (__attribute__((address_space(3))) void*)((char*)As + c * 4096 + wid * 1024),
                16, 0, 0);
            __builtin_amdgcn_global_load_lds(
                (const __attribute__((address_space(1))) void*)gb,
                (__attribute__((address_space(3))) void*)((char*)Bs + c * 4096 + wid * 1024),
                16, 0, 0);
        }
        __syncthreads();

        bf16x8 af[4][2], bfr[4][2];
#pragma unroll
        for (int m = 0; m < 4; ++m) {
            const int r = wr + m * 16 + (lane & 15);
            const char* base = (const char*)As + r * 128 + ((lane >> 4) * 16);
            af[m][0] = *(const bf16x8*)(base);
            af[m][1] = *(const bf16x8*)(base + 64);
        }
#pragma unroll
        for (int n = 0; n < 4; ++n) {
            const int r = wc + n * 16 + (lane & 15);
            const char* base = (const char*)Bs + r * 128 + ((lane >> 4) * 16);
            bfr[n][0] = *(const bf16x8*)(base);
            bfr[n][1] = *(const bf16x8*)(base + 64);
        }
#pragma unroll
        for (int m = 0; m < 4; ++m)
#pragma unroll
            for (int n = 0; n < 4; ++n) {
                acc[m][n] = __builtin_amdgcn_mfma_f32_16x16x32_bf16(af[m][0], bfr[n][0], acc[m][n], 0, 0, 0);
                acc[m][n] = __builtin_amdgcn_mfma_f32_16x16x32_bf16(af[m][1], bfr[n][1], acc[m][n], 0, 0, 0);
            }
    }

    // epilogue: C row = (lane>>4)*4 + reg, col = lane&15 (verified layout)
#pragma unroll
    for (int m = 0; m < 4; ++m) {
        const int rowb = mbase + wr + m * 16 + ((lane >> 4) * 4);
#pragma unroll
        for (int n = 0; n < 4; ++n) {
            const int col = nbase + wc + n * 16 + (lane & 15);
            const float bz = bias[col];
#pragma unroll
            for (int r = 0; r < 4; ++r) {
                float v = acc[m][n][r] + bz;
                if (relu) v = fmaxf(v, 0.f);
                C[(size_t)(rowb + r) * N + col] = f2bf(v);
            }
        }
    }
}

// ---------------- flash attention ----------------
// grid: (S/64, B*H); block 256 = 4 waves; each wave owns 16 q-rows.
// qkv layout: [tok][3072] with q at col 0, k at 1024, v at 2048 (+h*64).
__global__ __launch_bounds__(256) void attn_flash(const u16* __restrict__ qkv,
                                                  u16* __restrict__ att) {
    __shared__ __align__(16) u16 Ks[32 * 72];   // K tile, padded rows (72 elems = 144B)
    __shared__ __align__(16) u16 Vt[64 * 40];   // V^T tile, padded rows (40 elems = 80B)
    __shared__ __align__(16) u16 Ps[4][16 * 40];

    const int tid = threadIdx.x, wid = tid >> 6, lane = tid & 63;
    const int b = blockIdx.y >> 4, h = blockIdx.y & 15;
    const int qt = blockIdx.x;
    const size_t tok0 = (size_t)b * S_;

    const int qrow = qt * 64 + wid * 16 + (lane & 15);
    const u16* qp = qkv + (tok0 + qrow) * 3072 + h * 64;
    const bf16x8 qf0 = *(const bf16x8*)(qp + ((lane >> 4) * 8));
    const bf16x8 qf1 = *(const bf16x8*)(qp + 32 + ((lane >> 4) * 8));

    const u16* kp = qkv + tok0 * 3072 + 1024 + h * 64;
    const u16* vp = qkv + tok0 * 3072 + 2048 + h * 64;

    f32x4 accv[4];
    const f32x4 z = {0.f, 0.f, 0.f, 0.f};
#pragma unroll
    for (int nt = 0; nt < 4; ++nt) accv[nt] = z;
    float mrow[4] = {-1e30f, -1e30f, -1e30f, -1e30f};
    float lrow[4] = {0.f, 0.f, 0.f, 0.f};

    const int srow = tid >> 3;         // 0..31
    const int scb = (tid & 7) * 16;    // byte col within 128B of row data
    const int vd0 = (tid & 7) * 8;     // d-offset for V stage

    for (int kt = 0; kt < S_ / 32; ++kt) {
        __syncthreads();
        {   // stage K tile [32][64] (padded) and V^T tile [64][32] (padded)
            const u16* src = kp + (size_t)(kt * 32 + srow) * 3072 + (scb >> 1);
            *(uint4*)((char*)Ks + srow * 144 + scb) = *(const uint4*)src;
            const u16* vsrc = vp + (size_t)(kt * 32 + srow) * 3072 + vd0;
            uint4 vv = *(const uint4*)vsrc;
            const u16* pv = (const u16*)&vv;
#pragma unroll
            for (int e = 0; e < 8; ++e) Vt[(vd0 + e) * 40 + srow] = pv[e];
        }
        __syncthreads();

        // scores: 16 q-rows x 32 keys
        f32x4 sc0 = z, sc1 = z;
        {
            const char* kb0 = (const char*)Ks + (lane & 15) * 144 + ((lane >> 4) * 16);
            const bf16x8 k00 = *(const bf16x8*)(kb0);
            const bf16x8 k01 = *(const bf16x8*)(kb0 + 64);
            const char* kb1 = kb0 + 16 * 144;
            const bf16x8 k10 = *(const bf16x8*)(kb1);
            const bf16x8 k11 = *(const bf16x8*)(kb1 + 64);
            sc0 = __builtin_amdgcn_mfma_f32_16x16x32_bf16(qf0, k00, sc0, 0, 0, 0);
            sc0 = __builtin_amdgcn_mfma_f32_16x16x32_bf16(qf1, k01, sc0, 0, 0, 0);
            sc1 = __builtin_amdgcn_mfma_f32_16x16x32_bf16(qf0, k10, sc1, 0, 0, 0);
            sc1 = __builtin_amdgcn_mfma_f32_16x16x32_bf16(qf1, k11, sc1, 0, 0, 0);
        }

        // online softmax (row r lives in 16 lanes sharing lane>>4; cols = lane&15)
        float alpha[4];
#pragma unroll
        for (int r = 0; r < 4; ++r) {
            float s0 = sc0[r] * 0.125f, s1 = sc1[r] * 0.125f;
            float mx = fmaxf(s0, s1);
#pragma unroll
            for (int off = 1; off < 16; off <<= 1) mx = fmaxf(mx, __shfl_xor(mx, off));
            const float mnew = fmaxf(mrow[r], mx);
            const float al = __expf(mrow[r] - mnew);
            const float p0 = __expf(s0 - mnew);
            const float p1 = __expf(s1 - mnew);
            float rs = p0 + p1;
#pragma unroll
            for (int off = 1; off < 16; off <<= 1) rs += __shfl_xor(rs, off);
            mrow[r] = mnew;
            lrow[r] = al * lrow[r] + rs;
            alpha[r] = al;
            const int prow = (lane >> 4) * 4 + r;
            Ps[wid][prow * 40 + (lane & 15)] = f2bf(p0);
            Ps[wid][prow * 40 + 16 + (lane & 15)] = f2bf(p1);
        }
#pragma unroll
        for (int nt = 0; nt < 4; ++nt) {
            f32x4 t = accv[nt];
#pragma unroll
            for (int r = 0; r < 4; ++r) t[r] *= alpha[r];
            accv[nt] = t;
        }
        // PV: A = P (16x32), B = V (32xD) via Vt
        const bf16x8 pf = *(const bf16x8*)((const char*)Ps[wid] + (lane & 15) * 80 + ((lane >> 4) * 16));
#pragma unroll
        for (int nt = 0; nt < 4; ++nt) {
            const bf16x8 vf = *(const bf16x8*)((const char*)Vt + (nt * 16 + (lane & 15)) * 80 + ((lane >> 4) * 16));
            accv[nt] = __builtin_amdgcn_mfma_f32_16x16x32_bf16(pf, vf, accv[nt], 0, 0, 0);
        }
    }

    const size_t orow0 = tok0 + qt * 64 + wid * 16 + ((lane >> 4) * 4);
#pragma unroll
    for (int nt = 0; nt < 4; ++nt) {
        const int d = nt * 16 + (lane & 15);
#pragma unroll
        for (int r = 0; r < 4; ++r)
            att[(orow0 + r) * E_ + h * 64 + d] = f2bf(accv[nt][r] / lrow[r]);
    }
}

// ---------------- fused residual + layernorm ----------------
// t = xr + yb(bf16); out = LN(t)*g + b -> ho (f32) and optionally hb (bf16)
__global__ __launch_bounds__(256) void ln_fused(const float* __restrict__ xr,
                                                const u16* __restrict__ yb,
                                                const float* __restrict__ g,
                                                const float* __restrict__ bb,
                                                float* __restrict__ ho,
                                                u16* __restrict__ hb) {
    const int wid = threadIdx.x >> 6, lane = threadIdx.x & 63;
    const int row = blockIdx.x * 4 + wid;
    const float* xp = xr + (size_t)row * E_;
    const u16* yp = yb + (size_t)row * E_;

    f32x4 t[4];
    float sum = 0.f, ss = 0.f;
#pragma unroll
    for (int j = 0; j < 4; ++j) {
        const int idx = j * 256 + lane * 4;
        const f32x4 xv = *(const f32x4*)(xp + idx);
        const u16x4 yv = *(const u16x4*)(yp + idx);
        f32x4 tv;
#pragma unroll
        for (int e = 0; e < 4; ++e) tv[e] = xv[e] + bf2f(yv[e]);
        t[j] = tv;
        sum += tv[0] + tv[1] + tv[2] + tv[3];
        ss += tv[0] * tv[0] + tv[1] * tv[1] + tv[2] * tv[2] + tv[3] * tv[3];
    }
#pragma unroll
    for (int off = 1; off < 64; off <<= 1) {
        sum += __shfl_xor(sum, off);
        ss += __shfl_xor(ss, off);
    }
    const float mu = sum * (1.f / 1024.f);
    const float var = ss * (1.f / 1024.f) - mu * mu;
    const float rstd = rsqrtf(var + 1e-5f);
#pragma unroll
    for (int j = 0; j < 4; ++j) {
        const int idx = j * 256 + lane * 4;
        const f32x4 gv = *(const f32x4*)(g + idx);
        const f32x4 bv = *(const f32x4*)(bb + idx);
        f32x4 ov;
#pragma unroll
        for (int e = 0; e < 4; ++e) ov[e] = (t[j][e] - mu) * rstd * gv[e] + bv[e];
        *(f32x4*)(ho + (size_t)row * E_ + idx) = ov;
        if (hb) {
            u16x4 o4;
#pragma unroll
            for (int e = 0; e < 4; ++e) o4[e] = f2bf(ov[e]);
            *(u16x4*)(hb + (size_t)row * E_ + idx) = o4;
        }
    }
}

// ---------------- launch ----------------
extern "C" void kernel_launch(void* const* d_in, const int* in_sizes, int n_in,
                              void* d_out, int out_size, void* d_ws, size_t ws_size,
                              hipStream_t stream) {
    const float* x    = (const float*)d_in[0];
    const float* qw   = (const float*)d_in[1];
    const float* qb   = (const float*)d_in[2];
    const float* kw   = (const float*)d_in[3];
    const float* kb   = (const float*)d_in[4];
    const float* vw   = (const float*)d_in[5];
    const float* vb   = (const float*)d_in[6];
    const float* ow   = (const float*)d_in[7];
    const float* ob   = (const float*)d_in[8];
    const float* ln1g = (const float*)d_in[9];
    const float* ln1b = (const float*)d_in[10];
    const float* w1   = (const float*)d_in[11];
    const float* b1   = (const float*)d_in[12];
    const float* w2   = (const float*)d_in[13];
    const float* b2   = (const float*)d_in[14];
    const float* ln2g = (const float*)d_in[15];
    const float* ln2b = (const float*)d_in[16];

    if (ws_size < 192950272ull) return;  // workspace plan below needs ~193 MB

    char* ws = (char*)d_ws;
    u16*  wqkvT = (u16*)(ws + 0);               // [3072][1024] bf16
    u16*  woT   = (u16*)(ws + 6291456);          // [1024][1024]
    u16*  w1T   = (u16*)(ws + 8388608);          // [4096][1024]
    u16*  w2T   = (u16*)(ws + 16777216);         // [1024][4096]
    float* bqkv = (float*)(ws + 25165824);       // [3072]
    u16*  xb    = (u16*)(ws + 25178112);         // [8192][1024]  (then reused as att)
    u16*  attb  = xb;
    u16*  qkvb  = (u16*)(ws + 41955328);         // [8192][3072]  (then ao/hb/ff2)
    u16*  aob   = qkvb;
    u16*  hbb   = (u16*)(ws + 58732544);
    u16*  ff2b  = (u16*)(ws + 75509760);
    float* hf   = (float*)(ws + 92286976);       // [8192][1024] f32
    u16*  ff1b  = (u16*)(ws + 125841408);        // [8192][4096]

    cast_f32_bf16<<<dim3(4096), dim3(256), 0, stream>>>(x, xb);
    transpose_cast<<<dim3(32, 32), dim3(256), 0, stream>>>(qw, wqkvT, 1024, 1024);
    transpose_cast<<<dim3(32, 32), dim3(256), 0, stream>>>(kw, wqkvT + 1024 * 1024, 1024, 1024);
    transpose_cast<<<dim3(32, 32), dim3(256), 0, stream>>>(vw, wqkvT + 2048 * 1024, 1024, 1024);
    transpose_cast<<<dim3(32, 32), dim3(256), 0, stream>>>(ow, woT, 1024, 1024);
    transpose_cast<<<dim3(128, 32), dim3(256), 0, stream>>>(w1, w1T, 1024, 4096);
    transpose_cast<<<dim3(32, 128), dim3(256), 0, stream>>>(w2, w2T, 4096, 1024);
    concat_bias<<<dim3(12), dim3(256), 0, stream>>>(qb, kb, vb, bqkv);

    // QKV: [8192,1024] x [1024,3072]
    gemm_bf16<<<dim3(24, 64), dim3(256), 0, stream>>>(xb, wqkvT, bqkv, qkvb, 3072, 1024, 0);
    // attention
    attn_flash<<<dim3(32, 64), dim3(256), 0, stream>>>(qkvb, attb);
    // O-proj
    gemm_bf16<<<dim3(8, 64), dim3(256), 0, stream>>>(attb, woT, ob, aob, 1024, 1024, 0);
    // residual + LN1
    ln_fused<<<dim3(2048), dim3(256), 0, stream>>>(x, aob, ln1g, ln1b, hf, hbb);
    // FFN
    gemm_bf16<<<dim3(32, 64), dim3(256), 0, stream>>>(hbb, w1T, b1, ff1b, 4096, 1024, 1);
    gemm_bf16<<<dim3(8, 64), dim3(256), 0, stream>>>(ff1b, w2T, b2, ff2b, 1024, 4096, 0);
    // residual + LN2 -> output (f32)
    ln_fused<<<dim3(2048), dim3(256), 0, stream>>>(hf, ff2b, ln2g, ln2b, (float*)d_out, (u16*)nullptr);
}

// Round 4
// 752.805 us; speedup vs baseline: 1.0090x; 1.0090x over previous
//
#include <hip/hip_runtime.h>

typedef unsigned short u16;
typedef __attribute__((ext_vector_type(8))) short bf16x8;
typedef __attribute__((ext_vector_type(4))) float f32x4;
typedef __attribute__((ext_vector_type(8))) unsigned short u16x8;
typedef __attribute__((ext_vector_type(4))) unsigned short u16x4;

#define B_ 4
#define S_ 2048
#define E_ 1024
#define H_ 16
#define D_ 64
#define F_ 4096
#define M_ 8192   // B*S tokens

__device__ __forceinline__ float bf2f(u16 u) {
    union { unsigned int i; float f; } v; v.i = ((unsigned int)u) << 16; return v.f;
}
__device__ __forceinline__ u16 f2bf(float f) {
    union { float f; unsigned int i; } v; v.f = f;
    unsigned int r = v.i + 0x7FFFu + ((v.i >> 16) & 1u);
    return (u16)(r >> 16);
}

// ---------------- cast x (f32 -> bf16), 8 elems/thread ----------------
__global__ __launch_bounds__(256) void cast_f32_bf16(const float* __restrict__ in,
                                                     u16* __restrict__ out) {
    const int i = blockIdx.x * 256 + threadIdx.x;
    const f32x4* p = (const f32x4*)in + (size_t)i * 2;
    f32x4 a = p[0], b = p[1];
    u16x8 o;
    o[0] = f2bf(a[0]); o[1] = f2bf(a[1]); o[2] = f2bf(a[2]); o[3] = f2bf(a[3]);
    o[4] = f2bf(b[0]); o[5] = f2bf(b[1]); o[6] = f2bf(b[2]); o[7] = f2bf(b[3]);
    *((u16x8*)out + i) = o;
}

// ---------------- transpose + cast: w[R][C] f32 -> wT[C][R] bf16 ----------------
__global__ __launch_bounds__(256) void transpose_cast(const float* __restrict__ w,
                                                      u16* __restrict__ wT,
                                                      int R, int C) {
    __shared__ float tile[32][33];
    const int tx = threadIdx.x & 31, ty = threadIdx.x >> 5;
    const int c0 = blockIdx.x * 32, r0 = blockIdx.y * 32;
#pragma unroll
    for (int i = 0; i < 4; ++i)
        tile[ty + i * 8][tx] = w[(size_t)(r0 + ty + i * 8) * C + c0 + tx];
    __syncthreads();
#pragma unroll
    for (int i = 0; i < 4; ++i)
        wT[(size_t)(c0 + ty + i * 8) * R + r0 + tx] = f2bf(tile[tx][ty + i * 8]);
}

// ---------------- concat q/k/v bias into [3072] f32 ----------------
__global__ __launch_bounds__(256) void concat_bias(const float* __restrict__ qb,
                                                   const float* __restrict__ kb,
                                                   const float* __restrict__ vb,
                                                   float* __restrict__ dst) {
    const int i = blockIdx.x * 256 + threadIdx.x;
    float v = (i < 1024) ? qb[i] : ((i < 2048) ? kb[i - 1024] : vb[i - 2048]);
    dst[i] = v;
}

// ---------------- V transpose: qkv V-section -> vt[bh][d=64][s=2048] bf16 ----------------
__global__ __launch_bounds__(256) void transpose_v(const u16* __restrict__ qkv,
                                                   u16* __restrict__ vt) {
    __shared__ u16 t2[64 * 66];
    const int s0 = blockIdx.x * 64;
    const int bh = blockIdx.y;
    const int b = bh >> 4, h = bh & 15;
    const size_t base = ((size_t)b * S_) * 3072 + 2048 + (size_t)h * 64;
    const int t = threadIdx.x;
    const int sr = t >> 3, dc = (t & 7) * 8;
#pragma unroll
    for (int p = 0; p < 2; ++p) {
        const int s = sr + p * 32;
        u16x8 v = *(const u16x8*)(qkv + base + (size_t)(s0 + s) * 3072 + dc);
#pragma unroll
        for (int e = 0; e < 8; ++e) t2[(dc + e) * 66 + s] = v[e];
    }
    __syncthreads();
    const int dr = t >> 3, sc = (t & 7) * 8;
#pragma unroll
    for (int p = 0; p < 2; ++p) {
        const int d = dr + p * 32;
        u16x8 o;
#pragma unroll
        for (int e = 0; e < 8; ++e) o[e] = t2[d * 66 + sc + e];
        *(u16x8*)(vt + ((size_t)bh * 64 + d) * S_ + s0 + sc) = o;
    }
}

// ---------------- bf16 GEMM: C[M,N] = A[M,K] * Bt[N,K]^T + bias (+relu) ----------------
// 128x128 tile, BK=64, 4 waves (2x2), 16x16x32 MFMA, global_load_lds staging.
__global__ __launch_bounds__(256) void gemm_bf16(const u16* __restrict__ A,
                                                 const u16* __restrict__ Bt,
                                                 const float* __restrict__ bias,
                                                 u16* __restrict__ C,
                                                 int N, int K, int relu) {
    __shared__ __align__(16) u16 As[128 * 64];
    __shared__ __align__(16) u16 Bs[128 * 64];
    const int tid = threadIdx.x;
    const int wid = tid >> 6, lane = tid & 63;
    const int mbase = blockIdx.y * 128, nbase = blockIdx.x * 128;
    const int wr = (wid >> 1) * 64, wc = (wid & 1) * 64;

    f32x4 acc[4][4];
    const f32x4 z = {0.f, 0.f, 0.f, 0.f};
#pragma unroll
    for (int m = 0; m < 4; ++m)
#pragma unroll
        for (int n = 0; n < 4; ++n) acc[m][n] = z;

    const int Lb = wid * 1024 + lane * 16;  // byte offset within 16KB tile
    const int kIters = K >> 6;

    for (int kb = 0; kb < kIters; ++kb) {
        __syncthreads();
#pragma unroll
        for (int c = 0; c < 4; ++c) {
            const int L = c * 4096 + Lb;
            const int row = L >> 7;        // 128 bytes per row (64 bf16)
            const int cbyte = L & 127;
            const u16* ga = A + (size_t)(mbase + row) * K + (kb << 6) + (cbyte >> 1);
            const u16* gb = Bt + (size_t)(nbase + row) * K + (kb << 6) + (cbyte >> 1);
            __builtin_amdgcn_global_load_lds(
                (const __attribute__((address_space(1))) void*)ga,
                (__attribute__((address_space(3))) void*)((char*)As + c * 4096 + wid * 1024),
                16, 0, 0);
            __builtin_amdgcn_global_load_lds(
                (const __attribute__((address_space(1))) void*)gb,
                (__attribute__((address_space(3))) void*)((char*)Bs + c * 4096 + wid * 1024),
                16, 0, 0);
        }
        __syncthreads();

        bf16x8 af[4][2], bfr[4][2];
#pragma unroll
        for (int m = 0; m < 4; ++m) {
            const int r = wr + m * 16 + (lane & 15);
            const char* base = (const char*)As + r * 128 + ((lane >> 4) * 16);
            af[m][0] = *(const bf16x8*)(base);
            af[m][1] = *(const bf16x8*)(base + 64);
        }
#pragma unroll
        for (int n = 0; n < 4; ++n) {
            const int r = wc + n * 16 + (lane & 15);
            const char* base = (const char*)Bs + r * 128 + ((lane >> 4) * 16);
            bfr[n][0] = *(const bf16x8*)(base);
            bfr[n][1] = *(const bf16x8*)(base + 64);
        }
#pragma unroll
        for (int m = 0; m < 4; ++m)
#pragma unroll
            for (int n = 0; n < 4; ++n) {
                acc[m][n] = __builtin_amdgcn_mfma_f32_16x16x32_bf16(af[m][0], bfr[n][0], acc[m][n], 0, 0, 0);
                acc[m][n] = __builtin_amdgcn_mfma_f32_16x16x32_bf16(af[m][1], bfr[n][1], acc[m][n], 0, 0, 0);
            }
    }

    // epilogue: C row = (lane>>4)*4 + reg, col = lane&15 (verified layout)
#pragma unroll
    for (int m = 0; m < 4; ++m) {
        const int rowb = mbase + wr + m * 16 + ((lane >> 4) * 4);
#pragma unroll
        for (int n = 0; n < 4; ++n) {
            const int col = nbase + wc + n * 16 + (lane & 15);
            const float bz = bias[col];
#pragma unroll
            for (int r = 0; r < 4; ++r) {
                float v = acc[m][n][r] + bz;
                if (relu) v = fmaxf(v, 0.f);
                C[(size_t)(rowb + r) * N + col] = f2bf(v);
            }
        }
    }
}

// ---------------- flash attention v3: direct-L2 K/V fragments, padded-linear P ----------
// grid: (S/128, B*H); block 256 = 4 waves; each wave owns 32 q-rows.
// V from pre-transposed vt[bh][64][2048]. P via per-wave padded LDS (stride 72 u16).
#define PSTRIDE 72
__global__ __launch_bounds__(256) void attn_flash3(const u16* __restrict__ qkv,
                                                   const u16* __restrict__ vtg,
                                                   u16* __restrict__ att) {
    __shared__ __align__(16) u16 Ps[4][32 * PSTRIDE];
    const int tid = threadIdx.x, wid = tid >> 6, lane = tid & 63;
    const int bh = blockIdx.y, b = bh >> 4, h = bh & 15;
    const size_t tok0 = (size_t)b * S_;
    const int lg = lane >> 4, lr = lane & 15;

    const int q0 = blockIdx.x * 128 + wid * 32;

    bf16x8 qf[2][2];
#pragma unroll
    for (int qb = 0; qb < 2; ++qb) {
        const u16* qp = qkv + (tok0 + q0 + qb * 16 + lr) * 3072 + h * 64 + lg * 8;
        qf[qb][0] = *(const bf16x8*)qp;
        qf[qb][1] = *(const bf16x8*)(qp + 32);
    }
    const u16* kbase = qkv + tok0 * 3072 + 1024 + h * 64 + lg * 8;
    const u16* vbase = vtg + (size_t)bh * 64 * S_ + lg * 8;
    u16* Pw = Ps[wid];

    f32x4 accv[2][4];
    const f32x4 z = {0.f, 0.f, 0.f, 0.f};
#pragma unroll
    for (int qb = 0; qb < 2; ++qb)
#pragma unroll
        for (int nt = 0; nt < 4; ++nt) accv[qb][nt] = z;
    float mrow[2][4], lrow[2][4];
#pragma unroll
    for (int qb = 0; qb < 2; ++qb)
#pragma unroll
        for (int r = 0; r < 4; ++r) { mrow[qb][r] = -1e30f; lrow[qb][r] = 0.f; }

    for (int kt = 0; kt < S_ / 64; ++kt) {
        const int k0 = kt * 64;
        // ---- QK^T: K B-fragments direct from global (L2-resident) ----
        f32x4 sc[2][4];
        __builtin_amdgcn_s_setprio(1);
#pragma unroll
        for (int kb = 0; kb < 4; ++kb) {
            const u16* kp = kbase + (size_t)(k0 + kb * 16 + lr) * 3072;
            const bf16x8 kf0 = *(const bf16x8*)kp;
            const bf16x8 kf1 = *(const bf16x8*)(kp + 32);
#pragma unroll
            for (int qb = 0; qb < 2; ++qb) {
                sc[qb][kb] = __builtin_amdgcn_mfma_f32_16x16x32_bf16(qf[qb][0], kf0, z, 0, 0, 0);
                sc[qb][kb] = __builtin_amdgcn_mfma_f32_16x16x32_bf16(qf[qb][1], kf1, sc[qb][kb], 0, 0, 0);
            }
        }
        __builtin_amdgcn_s_setprio(0);

        // ---- online softmax: row = lg*4+r (per tile qb), key cols distributed over lr ----
        float alpha[2][4];
#pragma unroll
        for (int qb = 0; qb < 2; ++qb)
#pragma unroll
            for (int r = 0; r < 4; ++r) {
                const float v0 = sc[qb][0][r] * 0.125f, v1 = sc[qb][1][r] * 0.125f;
                const float v2 = sc[qb][2][r] * 0.125f, v3 = sc[qb][3][r] * 0.125f;
                float mx = fmaxf(fmaxf(v0, v1), fmaxf(v2, v3));
#pragma unroll
                for (int off = 1; off < 16; off <<= 1) mx = fmaxf(mx, __shfl_xor(mx, off));
                const float mold = mrow[qb][r];
                const float mnew = fmaxf(mold, mx);
                const float al = __expf(mold - mnew);
                alpha[qb][r] = al;
                mrow[qb][r] = mnew;
                const float p0 = __expf(v0 - mnew), p1 = __expf(v1 - mnew);
                const float p2 = __expf(v2 - mnew), p3 = __expf(v3 - mnew);
                float rs = (p0 + p1) + (p2 + p3);
#pragma unroll
                for (int off = 1; off < 16; off <<= 1) rs += __shfl_xor(rs, off);
                lrow[qb][r] = al * lrow[qb][r] + rs;
                // linear P: key kb*16+lr at u16 index rowP*PSTRIDE + kb*16 + lr
                const int rowP = qb * 16 + lg * 4 + r;
                Pw[rowP * PSTRIDE +  0 + lr] = f2bf(p0);
                Pw[rowP * PSTRIDE + 16 + lr] = f2bf(p1);
                Pw[rowP * PSTRIDE + 32 + lr] = f2bf(p2);
                Pw[rowP * PSTRIDE + 48 + lr] = f2bf(p3);
            }

        // rescale accumulator (alpha==1 when row max unchanged)
#pragma unroll
        for (int qb = 0; qb < 2; ++qb)
#pragma unroll
            for (int nt = 0; nt < 4; ++nt) {
                f32x4 t = accv[qb][nt];
#pragma unroll
                for (int r = 0; r < 4; ++r) t[r] *= alpha[qb][r];
                accv[qb][nt] = t;
            }

        __syncthreads();   // P writes -> P fragment reads (R2-proven fence)

        // ---- PV: A = P from LDS (linear padded), B = V^T direct from global ----
        bf16x8 pf[2][2];
#pragma unroll
        for (int qb = 0; qb < 2; ++qb) {
            const int rowP = qb * 16 + lr;
            pf[qb][0] = *(const bf16x8*)(Pw + rowP * PSTRIDE + lg * 8);
            pf[qb][1] = *(const bf16x8*)(Pw + rowP * PSTRIDE + 32 + lg * 8);
        }
        __builtin_amdgcn_s_setprio(1);
#pragma unroll
        for (int nt = 0; nt < 4; ++nt) {
            const u16* vp = vbase + (size_t)(nt * 16 + lr) * S_ + k0;
            const bf16x8 vt0 = *(const bf16x8*)vp;
            const bf16x8 vt1 = *(const bf16x8*)(vp + 32);
#pragma unroll
            for (int qb = 0; qb < 2; ++qb) {
                accv[qb][nt] = __builtin_amdgcn_mfma_f32_16x16x32_bf16(pf[qb][0], vt0, accv[qb][nt], 0, 0, 0);
                accv[qb][nt] = __builtin_amdgcn_mfma_f32_16x16x32_bf16(pf[qb][1], vt1, accv[qb][nt], 0, 0, 0);
            }
        }
        __builtin_amdgcn_s_setprio(0);
        __syncthreads();   // P reads done before next iteration's writes
    }

    // epilogue
#pragma unroll
    for (int qb = 0; qb < 2; ++qb) {
        float inv[4];
#pragma unroll
        for (int r = 0; r < 4; ++r) inv[r] = 1.0f / lrow[qb][r];
#pragma unroll
        for (int nt = 0; nt < 4; ++nt) {
            const int col = h * 64 + nt * 16 + lr;
#pragma unroll
            for (int r = 0; r < 4; ++r) {
                const size_t row = tok0 + q0 + qb * 16 + lg * 4 + r;
                att[row * E_ + col] = f2bf(accv[qb][nt][r] * inv[r]);
            }
        }
    }
}

// ---------------- fused residual + layernorm ----------------
__global__ __launch_bounds__(256) void ln_fused(const float* __restrict__ xr,
                                                const u16* __restrict__ yb,
                                                const float* __restrict__ g,
                                                const float* __restrict__ bb,
                                                float* __restrict__ ho,
                                                u16* __restrict__ hb) {
    const int wid = threadIdx.x >> 6, lane = threadIdx.x & 63;
    const int row = blockIdx.x * 4 + wid;
    const float* xp = xr + (size_t)row * E_;
    const u16* yp = yb + (size_t)row * E_;

    f32x4 t[4];
    float sum = 0.f, ss = 0.f;
#pragma unroll
    for (int j = 0; j < 4; ++j) {
        const int idx = j * 256 + lane * 4;
        const f32x4 xv = *(const f32x4*)(xp + idx);
        const u16x4 yv = *(const u16x4*)(yp + idx);
        f32x4 tv;
#pragma unroll
        for (int e = 0; e < 4; ++e) tv[e] = xv[e] + bf2f(yv[e]);
        t[j] = tv;
        sum += tv[0] + tv[1] + tv[2] + tv[3];
        ss += tv[0] * tv[0] + tv[1] * tv[1] + tv[2] * tv[2] + tv[3] * tv[3];
    }
#pragma unroll
    for (int off = 1; off < 64; off <<= 1) {
        sum += __shfl_xor(sum, off);
        ss += __shfl_xor(ss, off);
    }
    const float mu = sum * (1.f / 1024.f);
    const float var = ss * (1.f / 1024.f) - mu * mu;
    const float rstd = rsqrtf(var + 1e-5f);
#pragma unroll
    for (int j = 0; j < 4; ++j) {
        const int idx = j * 256 + lane * 4;
        const f32x4 gv = *(const f32x4*)(g + idx);
        const f32x4 bv = *(const f32x4*)(bb + idx);
        f32x4 ov;
#pragma unroll
        for (int e = 0; e < 4; ++e) ov[e] = (t[j][e] - mu) * rstd * gv[e] + bv[e];
        *(f32x4*)(ho + (size_t)row * E_ + idx) = ov;
        if (hb) {
            u16x4 o4;
#pragma unroll
            for (int e = 0; e < 4; ++e) o4[e] = f2bf(ov[e]);
            *(u16x4*)(hb + (size_t)row * E_ + idx) = o4;
        }
    }
}

// ---------------- launch ----------------
extern "C" void kernel_launch(void* const* d_in, const int* in_sizes, int n_in,
                              void* d_out, int out_size, void* d_ws, size_t ws_size,
                              hipStream_t stream) {
    const float* x    = (const float*)d_in[0];
    const float* qw   = (const float*)d_in[1];
    const float* qb   = (const float*)d_in[2];
    const float* kw   = (const float*)d_in[3];
    const float* kb   = (const float*)d_in[4];
    const float* vw   = (const float*)d_in[5];
    const float* vb   = (const float*)d_in[6];
    const float* ow   = (const float*)d_in[7];
    const float* ob   = (const float*)d_in[8];
    const float* ln1g = (const float*)d_in[9];
    const float* ln1b = (const float*)d_in[10];
    const float* w1   = (const float*)d_in[11];
    const float* b1   = (const float*)d_in[12];
    const float* w2   = (const float*)d_in[13];
    const float* b2   = (const float*)d_in[14];
    const float* ln2g = (const float*)d_in[15];
    const float* ln2b = (const float*)d_in[16];

    if (ws_size < 192950272ull) return;

    char* ws = (char*)d_ws;
    u16*  wqkvT = (u16*)(ws + 0);                // [3072][1024] bf16
    u16*  woT   = (u16*)(ws + 6291456);          // [1024][1024]
    u16*  w1T   = (u16*)(ws + 8388608);          // [4096][1024]
    u16*  w2T   = (u16*)(ws + 16777216);         // [1024][4096]
    float* bqkv = (float*)(ws + 25165824);       // [3072]
    u16*  xb    = (u16*)(ws + 25178112);         // [8192][1024]  (then reused as att)
    u16*  attb  = xb;
    u16*  qkvb  = (u16*)(ws + 41955328);         // [8192][3072]  (then ao)
    u16*  aob   = qkvb;
    u16*  vtg   = (u16*)(ws + 58732544);         // [64][64][2048] bf16 (dead before hbb)
    u16*  hbb   = (u16*)(ws + 58732544);         // reused after attention completes
    u16*  ff2b  = (u16*)(ws + 75509760);
    float* hf   = (float*)(ws + 92286976);       // [8192][1024] f32
    u16*  ff1b  = (u16*)(ws + 125841408);        // [8192][4096]

    cast_f32_bf16<<<dim3(4096), dim3(256), 0, stream>>>(x, xb);
    transpose_cast<<<dim3(32, 32), dim3(256), 0, stream>>>(qw, wqkvT, 1024, 1024);
    transpose_cast<<<dim3(32, 32), dim3(256), 0, stream>>>(kw, wqkvT + 1024 * 1024, 1024, 1024);
    transpose_cast<<<dim3(32, 32), dim3(256), 0, stream>>>(vw, wqkvT + 2048 * 1024, 1024, 1024);
    transpose_cast<<<dim3(32, 32), dim3(256), 0, stream>>>(ow, woT, 1024, 1024);
    transpose_cast<<<dim3(128, 32), dim3(256), 0, stream>>>(w1, w1T, 1024, 4096);
    transpose_cast<<<dim3(32, 128), dim3(256), 0, stream>>>(w2, w2T, 4096, 1024);
    concat_bias<<<dim3(12), dim3(256), 0, stream>>>(qb, kb, vb, bqkv);

    // QKV: [8192,1024] x [1024,3072]
    gemm_bf16<<<dim3(24, 64), dim3(256), 0, stream>>>(xb, wqkvT, bqkv, qkvb, 3072, 1024, 0);
    // V transpose for fragment-shaped PV reads
    transpose_v<<<dim3(32, 64), dim3(256), 0, stream>>>(qkvb, vtg);
    // attention
    attn_flash3<<<dim3(16, 64), dim3(256), 0, stream>>>(qkvb, vtg, attb);
    // O-proj
    gemm_bf16<<<dim3(8, 64), dim3(256), 0, stream>>>(attb, woT, ob, aob, 1024, 1024, 0);
    // residual + LN1
    ln_fused<<<dim3(2048), dim3(256), 0, stream>>>(x, aob, ln1g, ln1b, hf, hbb);
    // FFN
    gemm_bf16<<<dim3(32, 64), dim3(256), 0, stream>>>(hbb, w1T, b1, ff1b, 4096, 1024, 1);
    gemm_bf16<<<dim3(8, 64), dim3(256), 0, stream>>>(ff1b, w2T, b2, ff2b, 1024, 4096, 0);
    // residual + LN2 -> output (f32)
    ln_fused<<<dim3(2048), dim3(256), 0, stream>>>(hf, ff2b, ln2g, ln2b, (float*)d_out, (u16*)nullptr);
}

// Round 5
// 628.355 us; speedup vs baseline: 1.2088x; 1.1981x over previous
//
#include <hip/hip_runtime.h>
#include <hip/hip_bf16.h>

typedef unsigned short u16;
typedef __attribute__((ext_vector_type(8))) short bf16x8;
typedef __attribute__((ext_vector_type(4))) float f32x4;
typedef __attribute__((ext_vector_type(8))) unsigned short u16x8;
typedef __attribute__((ext_vector_type(4))) unsigned short u16x4;

#define B_ 4
#define S_ 2048
#define E_ 1024
#define H_ 16
#define D_ 64
#define F_ 4096
#define M_ 8192   // B*S tokens

__device__ __forceinline__ float bf2f(u16 u) {
    union { unsigned int i; float f; } v; v.i = ((unsigned int)u) << 16; return v.f;
}
__device__ __forceinline__ u16 f2bf(float f) {
    union { float f; unsigned int i; } v; v.f = f;
    unsigned int r = v.i + 0x7FFFu + ((v.i >> 16) & 1u);
    return (u16)(r >> 16);
}
__device__ __forceinline__ u16 f2bfh(float f) {
    __hip_bfloat16 h = __float2bfloat16(f);
    return *reinterpret_cast<u16*>(&h);
}

// ---------------- cast x (f32 -> bf16), 8 elems/thread ----------------
__global__ __launch_bounds__(256) void cast_f32_bf16(const float* __restrict__ in,
                                                     u16* __restrict__ out) {
    const int i = blockIdx.x * 256 + threadIdx.x;
    const f32x4* p = (const f32x4*)in + (size_t)i * 2;
    f32x4 a = p[0], b = p[1];
    u16x8 o;
    o[0] = f2bf(a[0]); o[1] = f2bf(a[1]); o[2] = f2bf(a[2]); o[3] = f2bf(a[3]);
    o[4] = f2bf(b[0]); o[5] = f2bf(b[1]); o[6] = f2bf(b[2]); o[7] = f2bf(b[3]);
    *((u16x8*)out + i) = o;
}

// ---------------- transpose + cast: w[R][C] f32 -> wT[C][R] bf16 ----------------
__global__ __launch_bounds__(256) void transpose_cast(const float* __restrict__ w,
                                                      u16* __restrict__ wT,
                                                      int R, int C) {
    __shared__ float tile[32][33];
    const int tx = threadIdx.x & 31, ty = threadIdx.x >> 5;
    const int c0 = blockIdx.x * 32, r0 = blockIdx.y * 32;
#pragma unroll
    for (int i = 0; i < 4; ++i)
        tile[ty + i * 8][tx] = w[(size_t)(r0 + ty + i * 8) * C + c0 + tx];
    __syncthreads();
#pragma unroll
    for (int i = 0; i < 4; ++i)
        wT[(size_t)(c0 + ty + i * 8) * R + r0 + tx] = f2bf(tile[tx][ty + i * 8]);
}

// ---------------- concat q/k/v bias into [3072] f32 ----------------
__global__ __launch_bounds__(256) void concat_bias(const float* __restrict__ qb,
                                                   const float* __restrict__ kb,
                                                   const float* __restrict__ vb,
                                                   float* __restrict__ dst) {
    const int i = blockIdx.x * 256 + threadIdx.x;
    float v = (i < 1024) ? qb[i] : ((i < 2048) ? kb[i - 1024] : vb[i - 2048]);
    dst[i] = v;
}

// ---------------- V transpose: qkv V-section -> vt[bh][d=64][s=2048] bf16 ----------------
__global__ __launch_bounds__(256) void transpose_v(const u16* __restrict__ qkv,
                                                   u16* __restrict__ vt) {
    __shared__ u16 t2[64 * 66];
    const int s0 = blockIdx.x * 64;
    const int bh = blockIdx.y;
    const int b = bh >> 4, h = bh & 15;
    const size_t base = ((size_t)b * S_) * 3072 + 2048 + (size_t)h * 64;
    const int t = threadIdx.x;
    const int sr = t >> 3, dc = (t & 7) * 8;
#pragma unroll
    for (int p = 0; p < 2; ++p) {
        const int s = sr + p * 32;
        u16x8 v = *(const u16x8*)(qkv + base + (size_t)(s0 + s) * 3072 + dc);
#pragma unroll
        for (int e = 0; e < 8; ++e) t2[(dc + e) * 66 + s] = v[e];
    }
    __syncthreads();
    const int dr = t >> 3, sc = (t & 7) * 8;
#pragma unroll
    for (int p = 0; p < 2; ++p) {
        const int d = dr + p * 32;
        u16x8 o;
#pragma unroll
        for (int e = 0; e < 8; ++e) o[e] = t2[d * 66 + sc + e];
        *(u16x8*)(vt + ((size_t)bh * 64 + d) * S_ + s0 + sc) = o;
    }
}

// ---------------- bf16 GEMM: C[M,N] = A[M,K] * Bt[N,K]^T + bias (+relu) ----------------
// 128x128 tile, BK=64, 4 waves (2x2), 16x16x32 MFMA, global_load_lds staging.
__global__ __launch_bounds__(256) void gemm_bf16(const u16* __restrict__ A,
                                                 const u16* __restrict__ Bt,
                                                 const float* __restrict__ bias,
                                                 u16* __restrict__ C,
                                                 int N, int K, int relu) {
    __shared__ __align__(16) u16 As[128 * 64];
    __shared__ __align__(16) u16 Bs[128 * 64];
    const int tid = threadIdx.x;
    const int wid = tid >> 6, lane = tid & 63;
    const int mbase = blockIdx.y * 128, nbase = blockIdx.x * 128;
    const int wr = (wid >> 1) * 64, wc = (wid & 1) * 64;

    f32x4 acc[4][4];
    const f32x4 z = {0.f, 0.f, 0.f, 0.f};
#pragma unroll
    for (int m = 0; m < 4; ++m)
#pragma unroll
        for (int n = 0; n < 4; ++n) acc[m][n] = z;

    const int Lb = wid * 1024 + lane * 16;  // byte offset within 16KB tile
    const int kIters = K >> 6;

    for (int kb = 0; kb < kIters; ++kb) {
        __syncthreads();
#pragma unroll
        for (int c = 0; c < 4; ++c) {
            const int L = c * 4096 + Lb;
            const int row = L >> 7;        // 128 bytes per row (64 bf16)
            const int cbyte = L & 127;
            const u16* ga = A + (size_t)(mbase + row) * K + (kb << 6) + (cbyte >> 1);
            const u16* gb = Bt + (size_t)(nbase + row) * K + (kb << 6) + (cbyte >> 1);
            __builtin_amdgcn_global_load_lds(
                (const __attribute__((address_space(1))) void*)ga,
                (__attribute__((address_space(3))) void*)((char*)As + c * 4096 + wid * 1024),
                16, 0, 0);
            __builtin_amdgcn_global_load_lds(
                (const __attribute__((address_space(1))) void*)gb,
                (__attribute__((address_space(3))) void*)((char*)Bs + c * 4096 + wid * 1024),
                16, 0, 0);
        }
        __syncthreads();

        bf16x8 af[4][2], bfr[4][2];
#pragma unroll
        for (int m = 0; m < 4; ++m) {
            const int r = wr + m * 16 + (lane & 15);
            const char* base = (const char*)As + r * 128 + ((lane >> 4) * 16);
            af[m][0] = *(const bf16x8*)(base);
            af[m][1] = *(const bf16x8*)(base + 64);
        }
#pragma unroll
        for (int n = 0; n < 4; ++n) {
            const int r = wc + n * 16 + (lane & 15);
            const char* base = (const char*)Bs + r * 128 + ((lane >> 4) * 16);
            bfr[n][0] = *(const bf16x8*)(base);
            bfr[n][1] = *(const bf16x8*)(base + 64);
        }
#pragma unroll
        for (int m = 0; m < 4; ++m)
#pragma unroll
            for (int n = 0; n < 4; ++n) {
                acc[m][n] = __builtin_amdgcn_mfma_f32_16x16x32_bf16(af[m][0], bfr[n][0], acc[m][n], 0, 0, 0);
                acc[m][n] = __builtin_amdgcn_mfma_f32_16x16x32_bf16(af[m][1], bfr[n][1], acc[m][n], 0, 0, 0);
            }
    }

    // epilogue: C row = (lane>>4)*4 + reg, col = lane&15 (verified layout)
#pragma unroll
    for (int m = 0; m < 4; ++m) {
        const int rowb = mbase + wr + m * 16 + ((lane >> 4) * 4);
#pragma unroll
        for (int n = 0; n < 4; ++n) {
            const int col = nbase + wc + n * 16 + (lane & 15);
            const float bz = bias[col];
#pragma unroll
            for (int r = 0; r < 4; ++r) {
                float v = acc[m][n][r] + bz;
                if (relu) v = fmaxf(v, 0.f);
                C[(size_t)(rowb + r) * N + col] = f2bf(v);
            }
        }
    }
}

// ---------------- flash attention v4 ----------------
// grid: (S/128, B*H); block 256 = 4 waves; each wave owns 32 q-rows.
// K tile: LDS double-buffered via global_load_lds with pre-swizzled source
//   (involution: colb ^= (row&7)<<4 on both source and read — rule 21).
// Staged one iteration ahead; mid-iter __syncthreads (vmcnt drain) is the fence.
// V: direct-global fragments issued at loop top (T14). P: wave-private LDS, linear padded.
// Softmax: exp2-domain, per-lane partial row-sums (one final reduce at end).
#define PSTRIDE 72
#define NT_ (S_ / 64)
__global__ __launch_bounds__(256) void attn_flash4(const u16* __restrict__ qkv,
                                                   const u16* __restrict__ vtg,
                                                   u16* __restrict__ att) {
    __shared__ __align__(16) u16 Kt[2][64 * 64];       // 8KB per buffer, swizzled
    __shared__ __align__(16) u16 Ps[4][32 * PSTRIDE];  // per-wave P
    const int tid = threadIdx.x, wid = tid >> 6, lane = tid & 63;
    const int bh = blockIdx.y, b = bh >> 4, h = bh & 15;
    const size_t tok0 = (size_t)b * S_;
    const int lg = lane >> 4, lr = lane & 15;
    const int q0 = blockIdx.x * 128 + wid * 32;

    // Q fragments (held in regs for the whole kernel)
    bf16x8 qf[2][2];
#pragma unroll
    for (int qb = 0; qb < 2; ++qb) {
        const u16* qp = qkv + (tok0 + q0 + qb * 16 + lr) * 3072 + h * 64 + lg * 8;
        qf[qb][0] = *(const bf16x8*)qp;
        qf[qb][1] = *(const bf16x8*)(qp + 32);
    }

    // K staging source (pre-swizzled per lane, loop-invariant base)
    const u16* kp = qkv + tok0 * 3072 + 1024 + h * 64;
    const int srow = wid * 8 + (lane >> 3);              // row for chunk c=0 (c=1 adds 32; (row&7) unchanged)
    const int scolb = ((lane & 7) * 16) ^ ((srow & 7) << 4);
    const u16* ksrc0 = kp + (size_t)srow * 3072 + (scolb >> 1);
    const u16* ksrc1 = kp + (size_t)(srow + 32) * 3072 + (scolb >> 1);

    const u16* vbase = vtg + (size_t)bh * 64 * S_ + lg * 8;
    u16* Pw = Ps[wid];

    f32x4 accv[2][4];
    const f32x4 z = {0.f, 0.f, 0.f, 0.f};
#pragma unroll
    for (int qb = 0; qb < 2; ++qb)
#pragma unroll
        for (int nt = 0; nt < 4; ++nt) accv[qb][nt] = z;
    float mrow[2][4], lrow[2][4];
#pragma unroll
    for (int qb = 0; qb < 2; ++qb)
#pragma unroll
        for (int r = 0; r < 4; ++r) { mrow[qb][r] = -1e30f; lrow[qb][r] = 0.f; }

    // prologue: stage tile 0 into buffer 0
    __builtin_amdgcn_global_load_lds(
        (const __attribute__((address_space(1))) void*)ksrc0,
        (__attribute__((address_space(3))) void*)((char*)Kt[0] + wid * 1024),
        16, 0, 0);
    __builtin_amdgcn_global_load_lds(
        (const __attribute__((address_space(1))) void*)ksrc1,
        (__attribute__((address_space(3))) void*)((char*)Kt[0] + 4096 + wid * 1024),
        16, 0, 0);
    __syncthreads();

    const float CSC = 0.125f * 1.44269504088896341f;   // log2(e)/8

    for (int kt = 0; kt < NT_; ++kt) {
        const int cur = kt & 1;
        // ---- stage next K tile (completes at this iter's barrier) ----
        if (kt + 1 < NT_) {
            const size_t adv = (size_t)(kt + 1) * 64 * 3072;
            __builtin_amdgcn_global_load_lds(
                (const __attribute__((address_space(1))) void*)(ksrc0 + adv),
                (__attribute__((address_space(3))) void*)((char*)Kt[cur ^ 1] + wid * 1024),
                16, 0, 0);
            __builtin_amdgcn_global_load_lds(
                (const __attribute__((address_space(1))) void*)(ksrc1 + adv),
                (__attribute__((address_space(3))) void*)((char*)Kt[cur ^ 1] + 4096 + wid * 1024),
                16, 0, 0);
        }
        // ---- V fragments for this tile: issue early, consume after softmax ----
        bf16x8 vf[4][2];
#pragma unroll
        for (int nt = 0; nt < 4; ++nt) {
            const u16* vp = vbase + (size_t)(nt * 16 + lr) * S_ + kt * 64;
            vf[nt][0] = *(const bf16x8*)vp;
            vf[nt][1] = *(const bf16x8*)(vp + 32);
        }
        // ---- K fragments from LDS (swizzled read, 2-way conflicts only) ----
        bf16x8 kf[4][2];
#pragma unroll
        for (int kb = 0; kb < 4; ++kb) {
            const int row = kb * 16 + lr, sw = (row & 7) << 4;
            const char* rbase = (const char*)Kt[cur] + row * 128;
            kf[kb][0] = *(const bf16x8*)(rbase + ((lg * 16) ^ sw));
            kf[kb][1] = *(const bf16x8*)(rbase + ((64 + lg * 16) ^ sw));
        }
        // ---- QK^T ----
        f32x4 sc[2][4];
        __builtin_amdgcn_s_setprio(1);
#pragma unroll
        for (int kb = 0; kb < 4; ++kb)
#pragma unroll
            for (int qb = 0; qb < 2; ++qb) {
                sc[qb][kb] = __builtin_amdgcn_mfma_f32_16x16x32_bf16(qf[qb][0], kf[kb][0], z, 0, 0, 0);
                sc[qb][kb] = __builtin_amdgcn_mfma_f32_16x16x32_bf16(qf[qb][1], kf[kb][1], sc[qb][kb], 0, 0, 0);
            }
        __builtin_amdgcn_s_setprio(0);

        // ---- online softmax (exp2 domain; per-lane partial sums) ----
        float alpha[2][4];
#pragma unroll
        for (int qb = 0; qb < 2; ++qb)
#pragma unroll
            for (int r = 0; r < 4; ++r) {
                const float v0 = sc[qb][0][r], v1 = sc[qb][1][r];
                const float v2 = sc[qb][2][r], v3 = sc[qb][3][r];
                float mx = fmaxf(fmaxf(v0, v1), fmaxf(v2, v3));
#pragma unroll
                for (int off = 1; off < 16; off <<= 1) mx = fmaxf(mx, __shfl_xor(mx, off));
                const float mold = mrow[qb][r];
                const float mnew = fmaxf(mold, mx * CSC);
                const float al = exp2f(mold - mnew);
                alpha[qb][r] = al;
                mrow[qb][r] = mnew;
                const float p0 = exp2f(__builtin_fmaf(v0, CSC, -mnew));
                const float p1 = exp2f(__builtin_fmaf(v1, CSC, -mnew));
                const float p2 = exp2f(__builtin_fmaf(v2, CSC, -mnew));
                const float p3 = exp2f(__builtin_fmaf(v3, CSC, -mnew));
                lrow[qb][r] = al * lrow[qb][r] + ((p0 + p1) + (p2 + p3));
                const int rowP = qb * 16 + lg * 4 + r;
                u16* pw = Pw + rowP * PSTRIDE + lr;
                pw[0]  = f2bfh(p0);
                pw[16] = f2bfh(p1);
                pw[32] = f2bfh(p2);
                pw[48] = f2bfh(p3);
            }
        // rescale accumulator
#pragma unroll
        for (int qb = 0; qb < 2; ++qb)
#pragma unroll
            for (int nt = 0; nt < 4; ++nt) {
                f32x4 t = accv[qb][nt];
#pragma unroll
                for (int r = 0; r < 4; ++r) t[r] *= alpha[qb][r];
                accv[qb][nt] = t;
            }

        __syncthreads();   // fences: P stores (lgkm) + K stage (vmcnt) + buffer flip

        // ---- PV: A = P from LDS, B = V^T from regs ----
        bf16x8 pf[2][2];
#pragma unroll
        for (int qb = 0; qb < 2; ++qb) {
            const int rowP = qb * 16 + lr;
            pf[qb][0] = *(const bf16x8*)(Pw + rowP * PSTRIDE + lg * 8);
            pf[qb][1] = *(const bf16x8*)(Pw + rowP * PSTRIDE + 32 + lg * 8);
        }
        __builtin_amdgcn_s_setprio(1);
#pragma unroll
        for (int nt = 0; nt < 4; ++nt)
#pragma unroll
            for (int qb = 0; qb < 2; ++qb) {
                accv[qb][nt] = __builtin_amdgcn_mfma_f32_16x16x32_bf16(pf[qb][0], vf[nt][0], accv[qb][nt], 0, 0, 0);
                accv[qb][nt] = __builtin_amdgcn_mfma_f32_16x16x32_bf16(pf[qb][1], vf[nt][1], accv[qb][nt], 0, 0, 0);
            }
        __builtin_amdgcn_s_setprio(0);
    }

    // epilogue: final cross-lane row-sum reduce, then normalize and store
#pragma unroll
    for (int qb = 0; qb < 2; ++qb) {
        float inv[4];
#pragma unroll
        for (int r = 0; r < 4; ++r) {
            float s = lrow[qb][r];
#pragma unroll
            for (int off = 1; off < 16; off <<= 1) s += __shfl_xor(s, off);
            inv[r] = 1.0f / s;
        }
#pragma unroll
        for (int nt = 0; nt < 4; ++nt) {
            const int col = h * 64 + nt * 16 + lr;
#pragma unroll
            for (int r = 0; r < 4; ++r) {
                const size_t row = tok0 + q0 + qb * 16 + lg * 4 + r;
                att[row * E_ + col] = f2bf(accv[qb][nt][r] * inv[r]);
            }
        }
    }
}

// ---------------- fused residual + layernorm ----------------
__global__ __launch_bounds__(256) void ln_fused(const float* __restrict__ xr,
                                                const u16* __restrict__ yb,
                                                const float* __restrict__ g,
                                                const float* __restrict__ bb,
                                                float* __restrict__ ho,
                                                u16* __restrict__ hb) {
    const int wid = threadIdx.x >> 6, lane = threadIdx.x & 63;
    const int row = blockIdx.x * 4 + wid;
    const float* xp = xr + (size_t)row * E_;
    const u16* yp = yb + (size_t)row * E_;

    f32x4 t[4];
    float sum = 0.f, ss = 0.f;
#pragma unroll
    for (int j = 0; j < 4; ++j) {
        const int idx = j * 256 + lane * 4;
        const f32x4 xv = *(const f32x4*)(xp + idx);
        const u16x4 yv = *(const u16x4*)(yp + idx);
        f32x4 tv;
#pragma unroll
        for (int e = 0; e < 4; ++e) tv[e] = xv[e] + bf2f(yv[e]);
        t[j] = tv;
        sum += tv[0] + tv[1] + tv[2] + tv[3];
        ss += tv[0] * tv[0] + tv[1] * tv[1] + tv[2] * tv[2] + tv[3] * tv[3];
    }
#pragma unroll
    for (int off = 1; off < 64; off <<= 1) {
        sum += __shfl_xor(sum, off);
        ss += __shfl_xor(ss, off);
    }
    const float mu = sum * (1.f / 1024.f);
    const float var = ss * (1.f / 1024.f) - mu * mu;
    const float rstd = rsqrtf(var + 1e-5f);
#pragma unroll
    for (int j = 0; j < 4; ++j) {
        const int idx = j * 256 + lane * 4;
        const f32x4 gv = *(const f32x4*)(g + idx);
        const f32x4 bv = *(const f32x4*)(bb + idx);
        f32x4 ov;
#pragma unroll
        for (int e = 0; e < 4; ++e) ov[e] = (t[j][e] - mu) * rstd * gv[e] + bv[e];
        *(f32x4*)(ho + (size_t)row * E_ + idx) = ov;
        if (hb) {
            u16x4 o4;
#pragma unroll
            for (int e = 0; e < 4; ++e) o4[e] = f2bf(ov[e]);
            *(u16x4*)(hb + (size_t)row * E_ + idx) = o4;
        }
    }
}

// ---------------- launch ----------------
extern "C" void kernel_launch(void* const* d_in, const int* in_sizes, int n_in,
                              void* d_out, int out_size, void* d_ws, size_t ws_size,
                              hipStream_t stream) {
    const float* x    = (const float*)d_in[0];
    const float* qw   = (const float*)d_in[1];
    const float* qb   = (const float*)d_in[2];
    const float* kw   = (const float*)d_in[3];
    const float* kb   = (const float*)d_in[4];
    const float* vw   = (const float*)d_in[5];
    const float* vb   = (const float*)d_in[6];
    const float* ow   = (const float*)d_in[7];
    const float* ob   = (const float*)d_in[8];
    const float* ln1g = (const float*)d_in[9];
    const float* ln1b = (const float*)d_in[10];
    const float* w1   = (const float*)d_in[11];
    const float* b1   = (const float*)d_in[12];
    const float* w2   = (const float*)d_in[13];
    const float* b2   = (const float*)d_in[14];
    const float* ln2g = (const float*)d_in[15];
    const float* ln2b = (const float*)d_in[16];

    if (ws_size < 192950272ull) return;

    char* ws = (char*)d_ws;
    u16*  wqkvT = (u16*)(ws + 0);                // [3072][1024] bf16
    u16*  woT   = (u16*)(ws + 6291456);          // [1024][1024]
    u16*  w1T   = (u16*)(ws + 8388608);          // [4096][1024]
    u16*  w2T   = (u16*)(ws + 16777216);         // [1024][4096]
    float* bqkv = (float*)(ws + 25165824);       // [3072]
    u16*  xb    = (u16*)(ws + 25178112);         // [8192][1024]  (then reused as att)
    u16*  attb  = xb;
    u16*  qkvb  = (u16*)(ws + 41955328);         // [8192][3072]  (then ao)
    u16*  aob   = qkvb;
    u16*  vtg   = (u16*)(ws + 58732544);         // [64][64][2048] bf16 (dead before hbb)
    u16*  hbb   = (u16*)(ws + 58732544);         // reused after attention completes
    u16*  ff2b  = (u16*)(ws + 75509760);
    float* hf   = (float*)(ws + 92286976);       // [8192][1024] f32
    u16*  ff1b  = (u16*)(ws + 125841408);        // [8192][4096]

    cast_f32_bf16<<<dim3(4096), dim3(256), 0, stream>>>(x, xb);
    transpose_cast<<<dim3(32, 32), dim3(256), 0, stream>>>(qw, wqkvT, 1024, 1024);
    transpose_cast<<<dim3(32, 32), dim3(256), 0, stream>>>(kw, wqkvT + 1024 * 1024, 1024, 1024);
    transpose_cast<<<dim3(32, 32), dim3(256), 0, stream>>>(vw, wqkvT + 2048 * 1024, 1024, 1024);
    transpose_cast<<<dim3(32, 32), dim3(256), 0, stream>>>(ow, woT, 1024, 1024);
    transpose_cast<<<dim3(128, 32), dim3(256), 0, stream>>>(w1, w1T, 1024, 4096);
    transpose_cast<<<dim3(32, 128), dim3(256), 0, stream>>>(w2, w2T, 4096, 1024);
    concat_bias<<<dim3(12), dim3(256), 0, stream>>>(qb, kb, vb, bqkv);

    // QKV: [8192,1024] x [1024,3072]
    gemm_bf16<<<dim3(24, 64), dim3(256), 0, stream>>>(xb, wqkvT, bqkv, qkvb, 3072, 1024, 0);
    // V transpose for fragment-shaped PV reads
    transpose_v<<<dim3(32, 64), dim3(256), 0, stream>>>(qkvb, vtg);
    // attention
    attn_flash4<<<dim3(16, 64), dim3(256), 0, stream>>>(qkvb, vtg, attb);
    // O-proj
    gemm_bf16<<<dim3(8, 64), dim3(256), 0, stream>>>(attb, woT, ob, aob, 1024, 1024, 0);
    // residual + LN1
    ln_fused<<<dim3(2048), dim3(256), 0, stream>>>(x, aob, ln1g, ln1b, hf, hbb);
    // FFN
    gemm_bf16<<<dim3(32, 64), dim3(256), 0, stream>>>(hbb, w1T, b1, ff1b, 4096, 1024, 1);
    gemm_bf16<<<dim3(8, 64), dim3(256), 0, stream>>>(ff1b, w2T, b2, ff2b, 1024, 4096, 0);
    // residual + LN2 -> output (f32)
    ln_fused<<<dim3(2048), dim3(256), 0, stream>>>(hf, ff2b, ln2g, ln2b, (float*)d_out, (u16*)nullptr);
}